// Round 6
// baseline (127.892 us; speedup 1.0000x reference)
//
#include <hip/hip_runtime.h>

#define IMG   512
#define NCLS  256
#define DIM   1024
#define HPW   32
#define TPB   8            // tokens (patches) per block
#define NT    1024         // 16 waves: 8 consumer + 8 producer
#define DC    128          // dims per chunk
#define NCH   (DIM / DC)   // 8 chunks

typedef short bf16x8 __attribute__((ext_vector_type(8)));
typedef float f32x4  __attribute__((ext_vector_type(4)));

__device__ inline ushort bf16rne(float v) {
    unsigned u = __float_as_uint(v);
    return (ushort)((u + 0x7fffu + ((u >> 16) & 1u)) >> 16);
}

__global__ __launch_bounds__(NT, 4)
void fused_semtok(const int* __restrict__ smap, const float* __restrict__ table,
                  const float* __restrict__ gamma, const float* __restrict__ beta,
                  float* __restrict__ out)
{
    // B chunk double buffer: [buf][dim 0..127][cls 0..255] bf16, 16B-unit columns
    // XOR-swizzled by (dim & 31).  2 x 64 KB = 128 KB.
    __shared__ ushort Bc[2][DC][NCLS];
    __shared__ ushort cntb[16][264];          // bf16 counts/256; rows 8..15 zero
    __shared__ float  red[8][2][4][2];        // [cons-wave][g][i][{s,s2}]
    unsigned* cnt = (unsigned*)&Bc[0][0][0];  // 8 KB alias; dead before staging

    const int t    = threadIdx.x;
    const int lane = t & 63;
    const int w    = t >> 6;                  // 16 waves
    const int c    = lane & 15;
    const int g    = lane >> 4;

    const int tok0 = blockIdx.x * TPB;
    const int b    = tok0 >> 10;
    const int ph   = (tok0 >> 5) & 31;
    const int pw0  = tok0 & 31;

    // ---- zero hist + cntb ----
    for (int i = t; i < TPB * NCLS; i += NT) cnt[i] = 0u;
    for (int i = t; i < 16 * 264;   i += NT) (&cntb[0][0])[i] = 0;
    __syncthreads();

    // ---- histogram: 8 patches = 16 rows x 128 cols, int2 per thread ----
    {
        const int row = t >> 6;               // 0..15
        const int col = (t * 2) & 127;
        const int2 q = *reinterpret_cast<const int2*>(
            smap + ((size_t)b * IMG + (size_t)(ph * 16 + row)) * IMG + pw0 * 16 + col);
        unsigned* hp = &cnt[(col >> 4) * NCLS];
        atomicAdd(&hp[min(max(q.x, 0), NCLS - 1)], 1u);
        atomicAdd(&hp[min(max(q.y, 0), NCLS - 1)], 1u);
    }
    __syncthreads();

    // ---- counts -> bf16(count/256), exact (<=8 significant bits) ----
    for (int i = t; i < TPB * NCLS; i += NT)
        cntb[i >> 8][i & 255] = (ushort)(__float_as_uint((float)cnt[i] * (1.f / 256.f)) >> 16);
    __syncthreads();
    // cnt region dead from here; Bc[0] may be overwritten.

    // ---- staging: chunk ch -> Bc[buf].  Unit = 8 cls x 1 dim (16B LDS write).
    // Lane reads 8 coalesced scalar dwords (64 lanes = 64 consecutive dims). ----
    auto stage = [&](int ch, int buf, int wv, int nw) {
        const int nu = 4096 / (nw * 64);      // units per lane
        #pragma unroll 4
        for (int u = 0; u < nu; ++u) {
            const int uid = (wv + u * nw) * 64 + lane;   // 0..4095
            const int dim = uid & 127;
            const int cg  = uid >> 7;                    // cls group (8 cls)
            const float* src = table + (size_t)(cg * 8) * DIM + ch * DC + dim;
            ushort h[8];
            #pragma unroll
            for (int j = 0; j < 8; ++j) h[j] = bf16rne(src[(size_t)j * DIM]);
            uint4 pk;
            pk.x = (unsigned)h[0] | ((unsigned)h[1] << 16);
            pk.y = (unsigned)h[2] | ((unsigned)h[3] << 16);
            pk.z = (unsigned)h[4] | ((unsigned)h[5] << 16);
            pk.w = (unsigned)h[6] | ((unsigned)h[7] << 16);
            const int cu = cg ^ (dim & 31);              // T2 swizzle (write side)
            *reinterpret_cast<uint4*>(&Bc[buf][dim][cu * 8]) = pk;
        }
    };

    const bool cons = (w < 8);
    bf16x8 afrag[8];
    f32x4  acc[NCH];

    stage(0, 0, w, 16);                        // all 16 waves stage chunk 0
    if (cons) {
        #pragma unroll
        for (int ks = 0; ks < 8; ++ks)
            afrag[ks] = *reinterpret_cast<const bf16x8*>(&cntb[c][ks * 32 + g * 8]);
        #pragma unroll
        for (int i = 0; i < NCH; ++i) acc[i] = (f32x4){0.f, 0.f, 0.f, 0.f};
    }
    __syncthreads();

    // ---- chunk loop: consumers MFMA chunk ch, producers stage ch+1 ----
    #pragma unroll
    for (int ch = 0; ch < NCH; ++ch) {
        if (cons) {
            const int row = w * 16 + c;        // dim within chunk
            const ushort* rp = &Bc[ch & 1][row][0];
            #pragma unroll
            for (int ks = 0; ks < 8; ++ks) {
                const int cu = (ks * 4 + g) ^ (row & 31);   // T2 swizzle (read side)
                const bf16x8 bfrag = *reinterpret_cast<const bf16x8*>(rp + cu * 8);
                acc[ch] = __builtin_amdgcn_mfma_f32_16x16x32_bf16(afrag[ks], bfrag, acc[ch], 0, 0, 0);
            }
        } else if (ch + 1 < NCH) {
            stage(ch + 1, (ch + 1) & 1, w - 8, 8);
        }
        __syncthreads();
    }

    // ---- pos-embed + LN partials (consumers) ----
    float ls[4] = {0, 0, 0, 0}, ls2[4] = {0, 0, 0, 0};
    if (cons) {
        #pragma unroll
        for (int ch = 0; ch < NCH; ++ch) {
            const int d = ch * DC + w * 16 + c;
            const float omega = exp2f((float)(d & 255) * (-13.287712379549449f / 256.f));
            const int quad = ch >> 1;          // d>>8
            if (quad < 2) {
                float sv, cv; __sincosf((float)ph * omega, &sv, &cv);
                const float v = (quad & 1) ? cv : sv;
                #pragma unroll
                for (int i = 0; i < 4; ++i) acc[ch][i] += v;
            } else {
                #pragma unroll
                for (int i = 0; i < 4; ++i) {
                    float sv, cv; __sincosf((float)(pw0 + g * 4 + i) * omega, &sv, &cv);
                    acc[ch][i] += (quad & 1) ? cv : sv;
                }
            }
            #pragma unroll
            for (int i = 0; i < 4; ++i) { ls[i] += acc[ch][i]; ls2[i] += acc[ch][i] * acc[ch][i]; }
        }
        #pragma unroll
        for (int off = 1; off < 16; off <<= 1) {
            #pragma unroll
            for (int i = 0; i < 4; ++i) {
                ls[i]  += __shfl_xor(ls[i],  off, 64);
                ls2[i] += __shfl_xor(ls2[i], off, 64);
            }
        }
        if (c == 0 && g < 2) {
            #pragma unroll
            for (int i = 0; i < 4; ++i) { red[w][g][i][0] = ls[i]; red[w][g][i][1] = ls2[i]; }
        }
    }
    __syncthreads();

    // ---- finalize LN + store (consumer lanes g<2 own valid rows 0..7) ----
    if (cons && g < 2) {
        float mu[4], rs[4];
        #pragma unroll
        for (int i = 0; i < 4; ++i) {
            float S = 0.f, S2 = 0.f;
            #pragma unroll
            for (int ww = 0; ww < 8; ++ww) { S += red[ww][g][i][0]; S2 += red[ww][g][i][1]; }
            mu[i] = S * (1.f / DIM);
            rs[i] = rsqrtf(S2 * (1.f / DIM) - mu[i] * mu[i] + 1e-5f);
        }
        #pragma unroll
        for (int ch = 0; ch < NCH; ++ch) {
            const int d = ch * DC + w * 16 + c;
            const float gv = gamma[d], bv = beta[d];
            #pragma unroll
            for (int i = 0; i < 4; ++i) {
                const int r = g * 4 + i;
                out[((size_t)tok0 + r) * DIM + d] = (acc[ch][i] - mu[i]) * rs[i] * gv + bv;
            }
        }
    }
}

extern "C" void kernel_launch(void* const* d_in, const int* in_sizes, int n_in,
                              void* d_out, int out_size, void* d_ws, size_t ws_size,
                              hipStream_t stream) {
    const int*   smap  = (const int*)d_in[0];
    const float* table = (const float*)d_in[1];
    const float* gamma = (const float*)d_in[2];
    const float* beta  = (const float*)d_in[3];
    float*       out   = (float*)d_out;

    const int batches = in_sizes[0] / (IMG * IMG);   // = 2
    const int tokens  = batches * HPW * HPW;         // 2048
    fused_semtok<<<tokens / TPB, NT, 0, stream>>>(smap, table, gamma, beta, out);
}

// Round 7
// 32.667 us; speedup vs baseline: 3.9150x; 3.9150x over previous
//
#include <hip/hip_runtime.h>

#define IMG   512
#define NCLS  256
#define DIM   1024
#define HPW   32
#define TM    32           // tokens per block = one patch-row
#define NT2   1024         // 16 waves

typedef short bf16x8 __attribute__((ext_vector_type(8)));
typedef float f32x4  __attribute__((ext_vector_type(4)));

__device__ inline ushort bf16rne(float v) {
    unsigned u = __float_as_uint(v);
    return (ushort)((u + 0x7fffu + ((u >> 16) & 1u)) >> 16);
}

// ---------- K1: table f32 [256 cls][1024 dim] -> Tt bf16 [1024 dim][256 cls] ----------
__global__ __launch_bounds__(256)
void transpose_table(const float* __restrict__ table, ushort* __restrict__ Tt)
{
    __shared__ ushort tile[64][66];
    const int c0 = blockIdx.x * 64;          // class tile
    const int d0 = blockIdx.y * 64;          // dim tile
    const int t  = threadIdx.x;

    #pragma unroll
    for (int it = 0; it < 16; ++it) {
        const int idx = it * 256 + t;
        const int cl  = idx >> 6, dl = idx & 63;          // coalesced along dims
        tile[dl][cl] = bf16rne(table[(size_t)(c0 + cl) * DIM + d0 + dl]);
    }
    __syncthreads();
    #pragma unroll
    for (int it = 0; it < 16; ++it) {
        const int idx = it * 256 + t;
        const int dl  = idx >> 6, cl = idx & 63;          // coalesced along classes
        Tt[(size_t)(d0 + dl) * NCLS + c0 + cl] = tile[dl][cl];
    }
}

// ---------- K2: hist (block-local) -> MFMA (32 tok x 1024 dim x 256 cls) -> pos -> LN ----
__global__ __launch_bounds__(NT2)
void gemm_fused(const int* __restrict__ smap, const ushort* __restrict__ Tt,
                const float* __restrict__ gamma, const float* __restrict__ beta,
                float* __restrict__ out)
{
    __shared__ unsigned cnt[TM * NCLS];       // 32 KB
    __shared__ ushort   cntb[TM][264];        // padded: stride 528 B -> conflict-free b128
    __shared__ float    red[16][2][4][4][2];  // [wave][mf][g][i][{s,s2}]  4 KB

    const int t    = threadIdx.x;
    const int lane = t & 63;
    const int w    = t >> 6;                  // wave owns dims [w*64, w*64+64)
    const int c    = lane & 15;
    const int g    = lane >> 4;

    const int m    = blockIdx.x;              // one patch-row
    const int tok0 = m * TM;
    const int b    = m >> 5;
    const int ph   = m & 31;

    // ---- zero + histogram (16 rows x 512 cols, 8 px/thread via 2x int4) ----
    #pragma unroll
    for (int i = t; i < TM * NCLS; i += NT2) cnt[i] = 0u;
    __syncthreads();
    {
        const int row = t >> 6;               // 0..15
        const int col = (t & 63) * 8;         // 0..504
        const int* bp = smap + ((size_t)b * IMG + (size_t)(ph * 16 + row)) * IMG + col;
        const int4 q0 = *reinterpret_cast<const int4*>(bp);
        const int4 q1 = *reinterpret_cast<const int4*>(bp + 4);
        unsigned* hp = &cnt[(col >> 4) * NCLS];
        atomicAdd(&hp[min(max(q0.x, 0), NCLS - 1)], 1u);
        atomicAdd(&hp[min(max(q0.y, 0), NCLS - 1)], 1u);
        atomicAdd(&hp[min(max(q0.z, 0), NCLS - 1)], 1u);
        atomicAdd(&hp[min(max(q0.w, 0), NCLS - 1)], 1u);
        atomicAdd(&hp[min(max(q1.x, 0), NCLS - 1)], 1u);
        atomicAdd(&hp[min(max(q1.y, 0), NCLS - 1)], 1u);
        atomicAdd(&hp[min(max(q1.z, 0), NCLS - 1)], 1u);
        atomicAdd(&hp[min(max(q1.w, 0), NCLS - 1)], 1u);
    }
    __syncthreads();

    // ---- counts -> bf16(count/256), exact ----
    #pragma unroll
    for (int i = t; i < TM * NCLS; i += NT2)
        cntb[i >> 8][i & 255] = (ushort)(__float_as_uint((float)cnt[i] * (1.f / 256.f)) >> 16);
    __syncthreads();

    // ---- A fragments in registers: af[mf][ks] = 8 cls for token row mf*16+c ----
    bf16x8 af[2][8];
    #pragma unroll
    for (int mf = 0; mf < 2; ++mf)
        #pragma unroll
        for (int ks = 0; ks < 8; ++ks)
            af[mf][ks] = *reinterpret_cast<const bf16x8*>(&cntb[mf * 16 + c][ks * 32 + g * 8]);

    // ---- MFMA K-loop, B straight from Tt (global, dwordx4 per fragment) ----
    f32x4 acc[2][4];
    #pragma unroll
    for (int mf = 0; mf < 2; ++mf)
        #pragma unroll
        for (int nf = 0; nf < 4; ++nf) acc[mf][nf] = (f32x4){0.f, 0.f, 0.f, 0.f};

    const ushort* bt = Tt + (size_t)(w * 64 + c) * NCLS + g * 8;
    #pragma unroll
    for (int ks = 0; ks < 8; ++ks) {
        bf16x8 bf[4];
        #pragma unroll
        for (int nf = 0; nf < 4; ++nf)
            bf[nf] = *reinterpret_cast<const bf16x8*>(bt + (size_t)nf * 16 * NCLS + ks * 32);
        #pragma unroll
        for (int nf = 0; nf < 4; ++nf)
            #pragma unroll
            for (int mf = 0; mf < 2; ++mf)
                acc[mf][nf] = __builtin_amdgcn_mfma_f32_16x16x32_bf16(af[mf][ks], bf[nf], acc[mf][nf], 0, 0, 0);
    }

    // ---- pos-embed + LN partials.  dim d = w*64+nf*16+c; D row r=g*4+i; token = tok0+mf*16+r ----
    const int quad   = w >> 2;                // d>>8, wave-constant
    const int cosSel = quad & 1;
    float ls[2][4]  = {{0,0,0,0},{0,0,0,0}};
    float ls2[2][4] = {{0,0,0,0},{0,0,0,0}};

    #pragma unroll
    for (int nf = 0; nf < 4; ++nf) {
        const int d = w * 64 + nf * 16 + c;
        const float omega = exp2f((float)(d & 255) * (-13.287712379549449f / 256.f));
        if (quad < 2) {                       // h-embed: depends only on ph
            float sv, cv; __sincosf((float)ph * omega, &sv, &cv);
            const float v = cosSel ? cv : sv;
            #pragma unroll
            for (int mf = 0; mf < 2; ++mf)
                #pragma unroll
                for (int i = 0; i < 4; ++i) acc[mf][nf][i] += v;
        } else {                              // w-embed: pw = mf*16 + g*4 + i
            #pragma unroll
            for (int mf = 0; mf < 2; ++mf)
                #pragma unroll
                for (int i = 0; i < 4; ++i) {
                    float sv, cv; __sincosf((float)(mf * 16 + g * 4 + i) * omega, &sv, &cv);
                    acc[mf][nf][i] += cosSel ? cv : sv;
                }
        }
        #pragma unroll
        for (int mf = 0; mf < 2; ++mf)
            #pragma unroll
            for (int i = 0; i < 4; ++i) {
                ls[mf][i]  += acc[mf][nf][i];
                ls2[mf][i] += acc[mf][nf][i] * acc[mf][nf][i];
            }
    }

    #pragma unroll
    for (int off = 1; off < 16; off <<= 1) {  // reduce over the 16 c-lanes (g preserved)
        #pragma unroll
        for (int mf = 0; mf < 2; ++mf)
            #pragma unroll
            for (int i = 0; i < 4; ++i) {
                ls[mf][i]  += __shfl_xor(ls[mf][i],  off, 64);
                ls2[mf][i] += __shfl_xor(ls2[mf][i], off, 64);
            }
    }
    if (c == 0) {
        #pragma unroll
        for (int mf = 0; mf < 2; ++mf)
            #pragma unroll
            for (int i = 0; i < 4; ++i) {
                red[w][mf][g][i][0] = ls[mf][i];
                red[w][mf][g][i][1] = ls2[mf][i];
            }
    }
    __syncthreads();

    // ---- finalize LN + store ----
    float mu[2][4], rs[2][4];
    #pragma unroll
    for (int mf = 0; mf < 2; ++mf)
        #pragma unroll
        for (int i = 0; i < 4; ++i) {
            float S = 0.f, S2 = 0.f;
            #pragma unroll
            for (int ww = 0; ww < 16; ++ww) { S += red[ww][mf][g][i][0]; S2 += red[ww][mf][g][i][1]; }
            mu[mf][i] = S * (1.f / DIM);
            rs[mf][i] = rsqrtf(S2 * (1.f / DIM) - mu[mf][i] * mu[mf][i] + 1e-5f);
        }

    #pragma unroll
    for (int nf = 0; nf < 4; ++nf) {
        const int d = w * 64 + nf * 16 + c;
        const float gv = gamma[d], bv = beta[d];
        #pragma unroll
        for (int mf = 0; mf < 2; ++mf)
            #pragma unroll
            for (int i = 0; i < 4; ++i) {
                const int r = g * 4 + i;
                out[(size_t)(tok0 + mf * 16 + r) * DIM + d] =
                    (acc[mf][nf][i] - mu[mf][i]) * rs[mf][i] * gv + bv;
            }
    }
}

extern "C" void kernel_launch(void* const* d_in, const int* in_sizes, int n_in,
                              void* d_out, int out_size, void* d_ws, size_t ws_size,
                              hipStream_t stream) {
    const int*   smap  = (const int*)d_in[0];
    const float* table = (const float*)d_in[1];
    const float* gamma = (const float*)d_in[2];
    const float* beta  = (const float*)d_in[3];
    float*       out   = (float*)d_out;
    ushort*      Tt    = (ushort*)d_ws;                  // 512 KB

    const int batches = in_sizes[0] / (IMG * IMG);       // = 2
    const int tokens  = batches * HPW * HPW;             // 2048

    dim3 tgrid(NCLS / 64, DIM / 64);                     // (4, 16)
    transpose_table<<<tgrid, 256, 0, stream>>>(table, Tt);
    gemm_fused<<<tokens / TM, NT2, 0, stream>>>(smap, Tt, gamma, beta, out);
}